// Round 9
// baseline (559.442 us; speedup 1.0000x reference)
//
#include <hip/hip_runtime.h>
#include <math.h>

// Problem: B=2, T=2048, C=1024, H=16, D=64.
// Input/output dtype is sniffed at runtime (f32 vs bf16) — see detect_k.
#define Bdim 2
#define Tdim 2048
#define Cdim 1024
#define Hdim 16
#define Ddim 64

typedef unsigned short u16;
typedef __attribute__((ext_vector_type(8))) short bf16x8;  // 8 bf16 = 4 VGPRs
typedef __attribute__((ext_vector_type(4))) float f32x4;

__device__ __forceinline__ float b2f(u16 s){
  union { float f; unsigned u; } v; v.u = ((unsigned)s) << 16; return v.f;
}
__device__ __forceinline__ u16 f2b(float f){
  union { float f; unsigned u; } v; v.f = f;
  unsigned r = v.u + 0x7fffu + ((v.u >> 16) & 1u);  // RNE
  return (u16)(r >> 16);
}
// flag-dispatched scalar load of an INPUT tensor element (bf=1: bf16, bf=0: f32)
__device__ __forceinline__ float loadf(const void* p, size_t i, int bf){
  float r;
  if(bf) r = b2f(((const u16*)p)[i]);
  else   r = ((const float*)p)[i];
  return r;
}
__device__ __forceinline__ f32x4 mfma16(bf16x8 a, bf16x8 b, f32x4 c){
  return __builtin_amdgcn_mfma_f32_16x16x32_bf16(a, b, c, 0, 0, 0);
}
// async global->LDS, 16B per lane: lds dest = (wave-uniform base) + lane*16,
// global src is per-lane. Dest must be LINEAR (no padding) — rule #21.
__device__ __forceinline__ void glds16(const u16* g, u16* l){
  __builtin_amdgcn_global_load_lds(
      (const __attribute__((address_space(1))) unsigned int*)g,
      (__attribute__((address_space(3))) unsigned int*)l, 16, 0, 0);
}

// ---------------- dtype sniffer -------------------------------------------
__global__ void detect_k(const u16* __restrict__ x, int* __restrict__ flag){
  if(threadIdx.x == 0 && blockIdx.x == 0){
    int sane = 0;
    for(int i = 0; i < 64; i++){
      int e = (x[i] >> 7) & 0xFF;
      sane += (e == 0 || (e >= 0x6E && e <= 0x8A)) ? 1 : 0;
    }
    *flag = (sane >= 56) ? 1 : 0;
  }
}

// ---------------- input convert (enc_hat -> bf16) -------------------------
__global__ __launch_bounds__(256) void cvt_k(const void* __restrict__ in,
    u16* __restrict__ out, int n, const int* __restrict__ flagp){
  int bf = *flagp;
  int i = blockIdx.x * 256 + threadIdx.x;
  if(i < n) out[i] = bf ? ((const u16*)in)[i] : f2b(((const float*)in)[i]);
}

// ---------------- weight transpose: in[K][N] -> out[N][K] (bf16) ----------
__global__ __launch_bounds__(256) void transpose_k(const void* __restrict__ in,
    u16* __restrict__ out, int K, int N, const int* __restrict__ flagp){
  __shared__ u16 tile[32][34];
  int bf = *flagp;
  int n0 = blockIdx.x * 32, k0 = blockIdx.y * 32;
  int tx = threadIdx.x & 31, ty = threadIdx.x >> 5;  // 32 x 8
  #pragma unroll
  for(int i = 0; i < 4; i++)
    tile[ty + i*8][tx] = f2b(loadf(in, (size_t)(k0 + ty + i*8) * N + n0 + tx, bf));
  __syncthreads();
  #pragma unroll
  for(int i = 0; i < 4; i++)
    out[(size_t)(n0 + ty + i*8) * K + k0 + tx] = tile[tx][ty + i*8];
}

// ---------------- LayerNorm over C=1024, one block per row ----------------
template<int SRC>
__global__ __launch_bounds__(256) void ln_k(const void* __restrict__ xin,
    const void* __restrict__ g, const void* __restrict__ be,
    u16* __restrict__ out, const int* __restrict__ flagp){
  __shared__ float red[256];
  int bf = *flagp;
  int row = blockIdx.x, t = threadIdx.x;
  float v[4]; float s = 0.f;
  #pragma unroll
  for(int i = 0; i < 4; i++){
    size_t idx = (size_t)row * Cdim + t + i*256;
    v[i] = (SRC == 1) ? ((const float*)xin)[idx] : loadf(xin, idx, bf);
    s += v[i];
  }
  red[t] = s; __syncthreads();
  for(int o = 128; o > 0; o >>= 1){ if(t < o) red[t] += red[t+o]; __syncthreads(); }
  float mu = red[0] * (1.f / Cdim);
  __syncthreads();
  s = 0.f;
  #pragma unroll
  for(int i = 0; i < 4; i++){ float d = v[i] - mu; s += d*d; }
  red[t] = s; __syncthreads();
  for(int o = 128; o > 0; o >>= 1){ if(t < o) red[t] += red[t+o]; __syncthreads(); }
  float rstd = rsqrtf(red[0] * (1.f / Cdim) + 1e-5f);
  u16* orow = out + (size_t)row * Cdim;
  #pragma unroll
  for(int i = 0; i < 4; i++){
    int c = t + i*256;
    orow[c] = f2b((v[i] - mu) * rstd * loadf(g, c, bf) + loadf(be, c, bf));
  }
}

// ---------------- MFMA GEMM (round-19: MODE 1 = dbuf BK64 for QKV/GELU) ---
// Round-18 post-mortem: BK=128 dbuf (MODE 2) took FINAL/RES off the top-5
// (FINAL 81 -> <77). New leader: fullM GELU (MODE 0) 77.7 us with measured
// Occupancy 20% — BELOW the 2-blocks/CU (25%) a 64 KB dbuf config allows,
// so MODE 0's nominal 4-blocks/CU TLP isn't realized. Fix: MODE 1 = dbuf
// BK=64 (64 KB LDS) for QKV (keeps exactly 2/CU: strict prefetch add) and
// fullM GELU (LDS cap 4->2/CU but usage already ~1.6/CU).
// MODE 0: single-buf BK64 | MODE 1: dbuf BK64 | MODE 2: dbuf BK128.
// Swizzle (both-sides XOR, conflicts measured 0) unchanged.
enum { EPI_QKV = 0, EPI_RES = 1, EPI_GELU = 2, EPI_FINAL = 3 };

template<int EPI, int KK, int MODE>
__global__ __launch_bounds__(256) void gemm_k(
    const u16* __restrict__ A, const u16* __restrict__ Bt, const void* __restrict__ bias,
    void* __restrict__ out0, void* __restrict__ out1, const void* __restrict__ res,
    int M, int N, int mofs, const int* __restrict__ flagp)
{
  const int K = KK;
  const int BK    = (MODE == 2) ? 128 : 64;
  const int TILEU = 128 * BK;                  // u16 per operand per buffer
  __shared__ u16 As[(MODE >= 1 ? 2 : 1) * 128 * ((MODE == 2) ? 128 : 64)];
  __shared__ u16 Bs[(MODE >= 1 ? 2 : 1) * 128 * ((MODE == 2) ? 128 : 64)];
  int bf = *flagp;
  int tid = threadIdx.x;
  // chunked XCD swizzle: contiguous wgid range per XCD (xcd = orig % 8)
  int nblk = (int)(gridDim.x * gridDim.y);
  int orig = (int)(blockIdx.y * gridDim.x + blockIdx.x);
  int wgid = (orig & 7) * (nblk >> 3) + (orig >> 3);
  int bx = wgid % (int)gridDim.x, by = wgid / (int)gridDim.x;
  int m0 = by * 128, n0 = bx * 128;
  int w = tid >> 6, l = tid & 63;
  int lq = l & 15, lk = l >> 4;
  int m_off = (w & 1) * 64, n_off = (w >> 1) * 64;
  // B base: EPI_QKV skip of unused K columns is BLOCK-uniform (1024%128==0)
  const u16* Bbase = Bt +
      (size_t)(n0 + ((EPI == EPI_QKV && n0 >= 1024) ? 1024 : 0)) * K;
  const u16* Abase = A + (size_t)m0 * K;
  // BK64 staging map (round-6 form): wave w rows w*32..+31, 4 insts x 8
  // rows; lane -> row l>>3, src col pre-swizzled (l&7)^((l>>3)&7).
  int grow = w * 32 + (l >> 3);
  int gcol = (((l & 7) ^ ((l >> 3) & 7))) * 8;
  const u16* Ab0 = Abase + (size_t)grow * K + gcol;
  const u16* Bb0 = Bbase + (size_t)grow * K + gcol;

  #define STAGE64(buf, k0)                                                  \
    do{ _Pragma("unroll")                                                   \
      for(int i = 0; i < 4; i++)                                            \
        glds16(Ab0 + (size_t)(i*8) * K + (k0),                              \
               &As[(buf)*TILEU + (w*32 + i*8) * 64]);                       \
      _Pragma("unroll")                                                     \
      for(int i = 0; i < 4; i++)                                            \
        glds16(Bb0 + (size_t)(i*8) * K + (k0),                              \
               &Bs[(buf)*TILEU + (w*32 + i*8) * 64]);                       \
    } while(0)

  // BK128 staging: 8 insts x 4 rows per operand per wave; row = w*32 +
  // i*4 + (l>>4); src col = ((l&15) ^ (row&15)) * 8. LDS dest linear.
  #define STAGE128(buf, k0)                                                 \
    do{ _Pragma("unroll")                                                   \
      for(int i = 0; i < 8; i++){                                           \
        int rr = i*4 + (l >> 4);                                            \
        int cc = ((l & 15) ^ ((rr + w*32) & 15)) * 8;                       \
        glds16(Abase + (size_t)(w*32 + rr) * K + (k0) + cc,                 \
               &As[(buf)*TILEU + (w*32 + i*4) * 128]);                      \
        glds16(Bbase + (size_t)(w*32 + rr) * K + (k0) + cc,                 \
               &Bs[(buf)*TILEU + (w*32 + i*4) * 128]);                      \
      }                                                                     \
    } while(0)

  #define STAGE(buf, k0)                                                    \
    do{ if(MODE == 2) STAGE128(buf, k0); else STAGE64(buf, k0); } while(0)

  f32x4 acc[4][4] = {};
  #define COMPUTE(buf)                                                         \
    do{ _Pragma("unroll")                                                      \
      for(int kk = 0; kk < (MODE == 2 ? 4 : 2); kk++){                         \
        bf16x8 af[4], bfr[4];                                                  \
        _Pragma("unroll")                                                      \
        for(int mb = 0; mb < 4; mb++)                                          \
          af[mb]  = *(const bf16x8*)&As[(buf)*TILEU +                          \
              (m_off + mb*16 + lq) * BK + (((kk*4 + lk) ^ (lq & (BK/8 - 1))) * 8)]; \
        _Pragma("unroll")                                                      \
        for(int nb = 0; nb < 4; nb++)                                          \
          bfr[nb] = *(const bf16x8*)&Bs[(buf)*TILEU +                          \
              (n_off + nb*16 + lq) * BK + (((kk*4 + lk) ^ (lq & (BK/8 - 1))) * 8)]; \
        _Pragma("unroll")                                                      \
        for(int mb = 0; mb < 4; mb++)                                          \
          _Pragma("unroll")                                                    \
          for(int nb = 0; nb < 4; nb++)                                        \
            acc[mb][nb] = mfma16(af[mb], bfr[nb], acc[mb][nb]);                \
      }                                                                        \
    } while(0)

  if(MODE >= 1){
    int cur = 0;
    STAGE(0, 0);
    __syncthreads();                 // vmcnt(0) drain: tile 0 resident
    for(int k0 = 0; k0 < K; k0 += BK){
      if(k0 + BK < K) STAGE(cur ^ 1, k0 + BK);   // prefetch BEFORE compute
      COMPUTE(cur);
      __syncthreads();               // drains this iter's glds; publishes
      cur ^= 1;
    }
  } else {
    for(int k0 = 0; k0 < K; k0 += 64){
      __syncthreads();               // all waves done reading previous tile
      STAGE64(0, k0);
      __syncthreads();               // vmcnt(0) drain: tile resident
      COMPUTE(0);
    }
  }
  #undef STAGE64
  #undef STAGE128
  #undef STAGE
  #undef COMPUTE

  // epilogue: C/D layout row=(l>>4)*4+r, col=l&15
  #pragma unroll
  for(int mb = 0; mb < 4; mb++)
  #pragma unroll
  for(int nb = 0; nb < 4; nb++){
    #pragma unroll
    for(int r = 0; r < 4; r++){
      int m = m0 + m_off + mb*16 + lk*4 + r;
      int n = n0 + n_off + nb*16 + lq;
      float v = acc[mb][nb][r];
      if(EPI == EPI_QKV){
        int bsrc = (n < 1024) ? n : n + 1024;
        v += loadf(bias, bsrc, bf);
        int bb = m / Tdim, t = m % Tdim;
        if(n < 1024){  // Q -> (B,H,T,D)
          int h = n >> 6, d = n & 63;
          ((u16*)out0)[(((size_t)(bb*Hdim + h)*Tdim + t) << 6) + d] = f2b(v);
        } else {       // V -> transposed (B,H,D,T) for PV B-fragments
          int nv = n - 1024; int h = nv >> 6, d = nv & 63;
          ((u16*)out1)[((size_t)(bb*Hdim + h)*Ddim + d)*Tdim + t] = f2b(v);
        }
      } else if(EPI == EPI_RES){        // x2(f32) = x(INPUT) + A@W + bias
        v += loadf(bias, n, bf) + loadf(res, (size_t)m*N + n, bf);
        ((float*)out0)[(size_t)m*N + n] = v;
      } else if(EPI == EPI_GELU){       // exact gelu -> bf16
        v += loadf(bias, n, bf);
        float gl = 0.5f * v * (1.0f + erff(v * 0.70710678118f));
        ((u16*)out0)[(size_t)m*N + n] = f2b(gl);
      } else {                          // FINAL: x2(f32) + A@W + bias -> OUT
        v += loadf(bias, n, bf) + ((const float*)res)[(size_t)m*N + n];
        size_t oi = (size_t)(mofs + m) * N + n;
        if(bf) ((u16*)out0)[oi] = f2b(v);
        else   ((float*)out0)[oi] = v;
      }
    }
  }
}

// ---------------- fused LIF attention (round-13: shared-tile LDS staging) -
// (unchanged: left the top-5 after round 13; tau hidden by block-coop
// double-buffered staging of the E/V tiles shared by rt=4k..4k+3.)
__global__ __launch_bounds__(256, 3) void attn_k(
    const u16* __restrict__ Q, const u16* __restrict__ Vt, const u16* __restrict__ E,
    const void* __restrict__ gain, const void* __restrict__ battn,
    u16* __restrict__ aout, const int* __restrict__ flagp)
{
  __shared__ u16 Es[2][64][72];    // 18 KB, padded rows (2-way bank max)
  __shared__ u16 Vs[2][64][72];    // 18 KB
  __shared__ u16 P[4][16][72];     // 9 KB, per-wave P band
  int bf = *flagp;
  int k  = 31 - (int)(blockIdx.x >> 5);   // LPT: heavy blocks first
  int bh = blockIdx.x & 31;
  int b = bh >> 4, h = bh & 15;
  int tid = threadIdx.x;
  int w = tid >> 6, l = tid & 63;
  int lq = l & 15, lk = l >> 4;
  int rt = k * 4 + w;              // all 4 rts share stmax = k exactly
  int qrow = rt * 16;
  const u16* Qb = Q  + (size_t)bh * Tdim * Ddim;
  const u16* Vb = Vt + (size_t)bh * Ddim * Tdim;
  const u16* Eh = E  + (size_t)h  * Tdim * Ddim;
  // staging map: 256 thr x 2 segs of 16B cover one 64x64 bf16 tile
  int srow = tid >> 3;             // 0..31 (and +32 for seg 1)
  int scol = (tid & 7) * 8;        // u16 col 0..56
  bf16x8 qf[2];
  #pragma unroll
  for(int ks = 0; ks < 2; ks++)
    qf[ks] = *(const bf16x8*)(Qb + (size_t)(qrow + lq) * Ddim + ks*32 + lk*8);
  float g4[4], b4[4];
  #pragma unroll
  for(int r = 0; r < 4; r++){
    int t = qrow + lk*4 + r;
    g4[r] = loadf(gain, h * Tdim + t, bf);
    b4[r] = loadf(battn, h * Tdim + t, bf);
  }
  bf16x8 onesf;
  #pragma unroll
  for(int j = 0; j < 8; j++) onesf[j] = (short)0x3F80;  // bf16 1.0
  f32x4 num[4] = {};
  f32x4 den4 = {0.f, 0.f, 0.f, 0.f};
  // prologue: stage tile 0 into buffer 0
  {
    bf16x8 e0 = *(const bf16x8*)(Eh + (size_t)(srow     ) * Ddim + scol);
    bf16x8 e1 = *(const bf16x8*)(Eh + (size_t)(srow + 32) * Ddim + scol);
    bf16x8 v0 = *(const bf16x8*)(Vb + (size_t)(srow     ) * Tdim + scol);
    bf16x8 v1 = *(const bf16x8*)(Vb + (size_t)(srow + 32) * Tdim + scol);
    *(bf16x8*)&Es[0][srow     ][scol] = e0;
    *(bf16x8*)&Es[0][srow + 32][scol] = e1;
    *(bf16x8*)&Vs[0][srow     ][scol] = v0;
    *(bf16x8*)&Vs[0][srow + 32][scol] = v1;
  }
  __syncthreads();
  for(int st = 0; st <= k; st++){
    int cur = st & 1;
    // issue next-tile global loads EARLY (latency hides under compute)
    bf16x8 pe0, pe1, pv0, pv1;
    if(st < k){
      pe0 = *(const bf16x8*)(Eh + (size_t)((st+1)*64 + srow     ) * Ddim + scol);
      pe1 = *(const bf16x8*)(Eh + (size_t)((st+1)*64 + srow + 32) * Ddim + scol);
      pv0 = *(const bf16x8*)(Vb + (size_t)(srow     ) * Tdim + (st+1)*64 + scol);
      pv1 = *(const bf16x8*)(Vb + (size_t)(srow + 32) * Tdim + (st+1)*64 + scol);
    }
    // QK^T from LDS
    f32x4 sc[4] = {};
    #pragma unroll
    for(int ks = 0; ks < 2; ks++){
      #pragma unroll
      for(int nb = 0; nb < 4; nb++){
        bf16x8 ef = *(const bf16x8*)&Es[cur][nb*16 + lq][ks*32 + lk*8];
        sc[nb] = mfma16(qf[ks], ef, sc[nb]);
      }
    }
    int diag = (st == k);          // wave-uniform: interior tiles skip mask
    #pragma unroll
    for(int nb = 0; nb < 4; nb++){
      #pragma unroll
      for(int r = 0; r < 4; r++){
        int sg = st*64 + nb*16 + lq;
        int qg = qrow + lk*4 + r;
        float I = fmaf(g4[r], sc[nb][r], b4[r]);
        float u = (I - 1.0f) * __builtin_amdgcn_rcpf(I);
        float L = __builtin_amdgcn_logf(u);
        float denom = fmaf(-0.013862944f, L, 0.002f);
        float e = __builtin_amdgcn_exp2f(0.18033688f * __builtin_amdgcn_rcpf(denom));
        float p = (I > 1.0000001f) ? e : 1.0f;
        if(diag) p = (sg <= qg) ? p : 0.f;
        P[w][lk*4 + r][nb*16 + lq] = f2b(p);
      }
    }
    // wave-private band: in-wave LDS RAW ordered by compiler lgkmcnt waits
    #pragma unroll
    for(int ks = 0; ks < 2; ks++){
      bf16x8 pf = *(const bf16x8*)&P[w][lq][ks*32 + lk*8];
      den4 = mfma16(pf, onesf, den4);   // rowsum -> denominator
      #pragma unroll
      for(int nb = 0; nb < 4; nb++){
        bf16x8 vf = *(const bf16x8*)&Vs[cur][nb*16 + lq][ks*32 + lk*8];
        num[nb] = mfma16(pf, vf, num[nb]);
      }
    }
    if(st < k){
      // write next tile into the other buffer (vmcnt wait auto-inserted),
      // then one barrier: everyone finished reading buf cur^1 last iter.
      *(bf16x8*)&Es[cur^1][srow     ][scol] = pe0;
      *(bf16x8*)&Es[cur^1][srow + 32][scol] = pe1;
      *(bf16x8*)&Vs[cur^1][srow     ][scol] = pv0;
      *(bf16x8*)&Vs[cur^1][srow + 32][scol] = pv1;
      __syncthreads();
    }
  }
  float rden[4];
  #pragma unroll
  for(int r = 0; r < 4; r++) rden[r] = __builtin_amdgcn_rcpf(den4[r]);
  #pragma unroll
  for(int nb = 0; nb < 4; nb++){
    #pragma unroll
    for(int r = 0; r < 4; r++){
      int t = qrow + lk*4 + r;
      int d = nb*16 + lq;
      float o = num[nb][r] * rden[r];
      aout[((size_t)b * Tdim + t) * Cdim + h * Ddim + d] = f2b(o);
    }
  }
}

// --------------------------------------------------------------------------
// Arena (round-8 layout, the measured-best config):
//   flag@0 | R0(8M): xn -> attn_out -> W1t | R1(8M): Wqkv_t -> Wout_t -> W2t
//   | x2(16M f32) | R3a(8M): Q -> hn | R3b(8M): V^T -> gelu quarter | Ebf(4M)
//   | gbuf(32M) @52M iff ws_size >= 85MB -> FULL-M MLP (ran in round 8:
//   GELU 1024 blocks, FINAL 256 blocks — the 563 us path).
extern "C" void kernel_launch(void* const* d_in, const int* in_sizes, int n_in,
                              void* d_out, int out_size, void* d_ws, size_t ws_size,
                              hipStream_t stream)
{
  const void* x      = d_in[0];
  const void* ln1_g  = d_in[1];
  const void* ln1_b  = d_in[2];
  const void* qkv_w  = d_in[3];
  const void* qkv_b  = d_in[4];
  const void* out_w  = d_in[5];
  const void* out_b  = d_in[6];
  const void* ln2_g  = d_in[7];
  const void* ln2_b  = d_in[8];
  const void* mlp_w1 = d_in[9];
  const void* mlp_b1 = d_in[10];
  const void* mlp_w2 = d_in[11];
  const void* mlp_b2 = d_in[12];
  const void* enc    = d_in[13];
  const void* gain   = d_in[14];
  const void* battn  = d_in[15];
  (void)in_sizes; (void)n_in; (void)out_size;

  const size_t MB = 1024 * 1024;
  char* ws = (char*)d_ws;
  int*   flag = (int*)(ws);
  u16*   R0   = (u16*)(ws + 256);
  u16*   R1   = (u16*)(ws + 256 + 8*MB);
  float* x2   = (float*)(ws + 256 + 16*MB);
  u16*   R3a  = (u16*)(ws + 256 + 32*MB);
  u16*   R3b  = (u16*)(ws + 256 + 40*MB);
  u16*   Ebf  = (u16*)(ws + 256 + 48*MB);
  u16*   gbuf = (u16*)(ws + 256 + 52*MB);
  bool fullM = ws_size >= 85*MB;

  dim3 blk(256);
  detect_k<<<1, 64, 0, stream>>>((const u16*)x, flag);
  ln_k<0><<<4096, blk, 0, stream>>>(x, ln1_g, ln1_b, R0, flag);
  transpose_k<<<dim3(3072/32, 1024/32), blk, 0, stream>>>(qkv_w, R1, 1024, 3072, flag);
  cvt_k<<<(Hdim*Tdim*Ddim)/256, blk, 0, stream>>>(enc, Ebf, Hdim*Tdim*Ddim, flag);
  gemm_k<EPI_QKV,1024,1><<<dim3(2048/128, 4096/128), blk, 0, stream>>>(
      R0, R1, qkv_b, R3a, R3b, nullptr, 4096, 2048, 0, flag);
  attn_k<<<dim3(32*32), dim3(256), 0, stream>>>(R3a, R3b, Ebf, gain, battn, R0, flag);
  transpose_k<<<dim3(1024/32, 1024/32), blk, 0, stream>>>(out_w, R1, 1024, 1024, flag);
  gemm_k<EPI_RES,1024,2><<<dim3(1024/128, 4096/128), blk, 0, stream>>>(
      R0, R1, out_b, x2, nullptr, x, 4096, 1024, 0, flag);
  ln_k<1><<<4096, blk, 0, stream>>>(x2, ln2_g, ln2_b, R3a, flag);
  transpose_k<<<dim3(4096/32, 1024/32), blk, 0, stream>>>(mlp_w1, R0, 1024, 4096, flag);
  transpose_k<<<dim3(1024/32, 4096/32), blk, 0, stream>>>(mlp_w2, R1, 4096, 1024, flag);
  if(fullM){
    gemm_k<EPI_GELU,1024,1><<<dim3(4096/128, 4096/128), blk, 0, stream>>>(
        R3a, R0, mlp_b1, gbuf, nullptr, nullptr, 4096, 4096, 0, flag);
    gemm_k<EPI_FINAL,4096,2><<<dim3(1024/128, 4096/128), blk, 0, stream>>>(
        gbuf, R1, mlp_b2, d_out, nullptr, x2, 4096, 1024, 0, flag);
  } else {
    for(int q = 0; q < 4; q++){
      int ro = q * 1024;
      gemm_k<EPI_GELU,1024,2><<<dim3(4096/128, 1024/128), blk, 0, stream>>>(
          R3a + (size_t)ro*1024, R0, mlp_b1, R3b, nullptr, nullptr, 1024, 4096, 0, flag);
      gemm_k<EPI_FINAL,4096,2><<<dim3(1024/128, 1024/128), blk, 0, stream>>>(
          R3b, R1, mlp_b2, d_out, nullptr, x2 + (size_t)ro*1024, 1024, 1024, ro, flag);
    }
  }
}

// Round 10
// 484.634 us; speedup vs baseline: 1.1544x; 1.1544x over previous
//
#include <hip/hip_runtime.h>
#include <math.h>

// Problem: B=2, T=2048, C=1024, H=16, D=64.
// Input/output dtype is sniffed at runtime (f32 vs bf16) — see detect_k.
#define Bdim 2
#define Tdim 2048
#define Cdim 1024
#define Hdim 16
#define Ddim 64

typedef unsigned short u16;
typedef __attribute__((ext_vector_type(8))) short bf16x8;  // 8 bf16 = 4 VGPRs
typedef __attribute__((ext_vector_type(4))) float f32x4;

__device__ __forceinline__ float b2f(u16 s){
  union { float f; unsigned u; } v; v.u = ((unsigned)s) << 16; return v.f;
}
__device__ __forceinline__ u16 f2b(float f){
  union { float f; unsigned u; } v; v.f = f;
  unsigned r = v.u + 0x7fffu + ((v.u >> 16) & 1u);  // RNE
  return (u16)(r >> 16);
}
// flag-dispatched scalar load of an INPUT tensor element (bf=1: bf16, bf=0: f32)
__device__ __forceinline__ float loadf(const void* p, size_t i, int bf){
  float r;
  if(bf) r = b2f(((const u16*)p)[i]);
  else   r = ((const float*)p)[i];
  return r;
}
__device__ __forceinline__ f32x4 mfma16(bf16x8 a, bf16x8 b, f32x4 c){
  return __builtin_amdgcn_mfma_f32_16x16x32_bf16(a, b, c, 0, 0, 0);
}
// async global->LDS, 16B per lane: lds dest = (wave-uniform base) + lane*16,
// global src is per-lane. Dest must be LINEAR (no padding) — rule #21.
__device__ __forceinline__ void glds16(const u16* g, u16* l){
  __builtin_amdgcn_global_load_lds(
      (const __attribute__((address_space(1))) unsigned int*)g,
      (__attribute__((address_space(3))) unsigned int*)l, 16, 0, 0);
}

// ---------------- dtype sniffer -------------------------------------------
__global__ void detect_k(const u16* __restrict__ x, int* __restrict__ flag){
  if(threadIdx.x == 0 && blockIdx.x == 0){
    int sane = 0;
    for(int i = 0; i < 64; i++){
      int e = (x[i] >> 7) & 0xFF;
      sane += (e == 0 || (e >= 0x6E && e <= 0x8A)) ? 1 : 0;
    }
    *flag = (sane >= 56) ? 1 : 0;
  }
}

// ---------------- input convert (enc_hat -> bf16) -------------------------
__global__ __launch_bounds__(256) void cvt_k(const void* __restrict__ in,
    u16* __restrict__ out, int n, const int* __restrict__ flagp){
  int bf = *flagp;
  int i = blockIdx.x * 256 + threadIdx.x;
  if(i < n) out[i] = bf ? ((const u16*)in)[i] : f2b(((const float*)in)[i]);
}

// ---------------- weight transpose: in[K][N] -> out[N][K] (bf16) ----------
__global__ __launch_bounds__(256) void transpose_k(const void* __restrict__ in,
    u16* __restrict__ out, int K, int N, const int* __restrict__ flagp){
  __shared__ u16 tile[32][34];
  int bf = *flagp;
  int n0 = blockIdx.x * 32, k0 = blockIdx.y * 32;
  int tx = threadIdx.x & 31, ty = threadIdx.x >> 5;  // 32 x 8
  #pragma unroll
  for(int i = 0; i < 4; i++)
    tile[ty + i*8][tx] = f2b(loadf(in, (size_t)(k0 + ty + i*8) * N + n0 + tx, bf));
  __syncthreads();
  #pragma unroll
  for(int i = 0; i < 4; i++)
    out[(size_t)(n0 + ty + i*8) * K + k0 + tx] = tile[tx][ty + i*8];
}

// ---------------- LayerNorm over C=1024, one block per row ----------------
template<int SRC>
__global__ __launch_bounds__(256) void ln_k(const void* __restrict__ xin,
    const void* __restrict__ g, const void* __restrict__ be,
    u16* __restrict__ out, const int* __restrict__ flagp){
  __shared__ float red[256];
  int bf = *flagp;
  int row = blockIdx.x, t = threadIdx.x;
  float v[4]; float s = 0.f;
  #pragma unroll
  for(int i = 0; i < 4; i++){
    size_t idx = (size_t)row * Cdim + t + i*256;
    v[i] = (SRC == 1) ? ((const float*)xin)[idx] : loadf(xin, idx, bf);
    s += v[i];
  }
  red[t] = s; __syncthreads();
  for(int o = 128; o > 0; o >>= 1){ if(t < o) red[t] += red[t+o]; __syncthreads(); }
  float mu = red[0] * (1.f / Cdim);
  __syncthreads();
  s = 0.f;
  #pragma unroll
  for(int i = 0; i < 4; i++){ float d = v[i] - mu; s += d*d; }
  red[t] = s; __syncthreads();
  for(int o = 128; o > 0; o >>= 1){ if(t < o) red[t] += red[t+o]; __syncthreads(); }
  float rstd = rsqrtf(red[0] * (1.f / Cdim) + 1e-5f);
  u16* orow = out + (size_t)row * Cdim;
  #pragma unroll
  for(int i = 0; i < 4; i++){
    int c = t + i*256;
    orow[c] = f2b((v[i] - mu) * rstd * loadf(g, c, bf) + loadf(be, c, bf));
  }
}

// ---------------- MFMA GEMM (round-20: revert r9; MODE 3 = A-direct) ------
// Round-19 post-mortem: MODE 1 (dbuf BK64) REGRESSED GELU 77.7->124.7 and
// QKV — the 20% occupancy reading hid real 4-blocks/CU TLP. Revised model
// fitting all rounds: GELU/MODE 0 at 4 blocks/CU is LDS-PORT-bound
// (~770 cy/block-step x 4 = measured 2900 cy/CU-step); at 2 blocks the
// port can't be kept fed -> latency exposed (m132 re-confirmed).
// This round: revert QKV/GELU to round-8 modes; NEW MODE 3 for fullM GELU
// = single-buffer B-only LDS + A-operand DIRECT global(L2)->reg (per-lane
// fragment addressing, same pattern as attn's Q load). Removes A's stage-
// writes AND ds_reads = half the LDS-port bytes; A re-reads (2x) hit L2
// (XCD-swizzled panels). LDS 16 KB -> still 4 blocks/CU (grid-limited).
// MODE 0: single BK64 | 1: dbuf BK64 (unused) | 2: dbuf BK128 | 3: A-direct.
enum { EPI_QKV = 0, EPI_RES = 1, EPI_GELU = 2, EPI_FINAL = 3 };

template<int EPI, int KK, int MODE>
__global__ __launch_bounds__(256) void gemm_k(
    const u16* __restrict__ A, const u16* __restrict__ Bt, const void* __restrict__ bias,
    void* __restrict__ out0, void* __restrict__ out1, const void* __restrict__ res,
    int M, int N, int mofs, const int* __restrict__ flagp)
{
  const int K = KK;
  const int BK    = (MODE == 2) ? 128 : 64;
  const int TILEU = 128 * BK;                  // u16 per operand per buffer
  __shared__ u16 As[(MODE == 3) ? 16 :
                    ((MODE == 1 || MODE == 2) ? 2 : 1) * 128 * ((MODE == 2) ? 128 : 64)];
  __shared__ u16 Bs[((MODE == 1 || MODE == 2) ? 2 : 1) * 128 * ((MODE == 2) ? 128 : 64)];
  int bf = *flagp;
  int tid = threadIdx.x;
  // chunked XCD swizzle: contiguous wgid range per XCD (xcd = orig % 8)
  int nblk = (int)(gridDim.x * gridDim.y);
  int orig = (int)(blockIdx.y * gridDim.x + blockIdx.x);
  int wgid = (orig & 7) * (nblk >> 3) + (orig >> 3);
  int bx = wgid % (int)gridDim.x, by = wgid / (int)gridDim.x;
  int m0 = by * 128, n0 = bx * 128;
  int w = tid >> 6, l = tid & 63;
  int lq = l & 15, lk = l >> 4;
  int m_off = (w & 1) * 64, n_off = (w >> 1) * 64;
  // B base: EPI_QKV skip of unused K columns is BLOCK-uniform (1024%128==0)
  const u16* Bbase = Bt +
      (size_t)(n0 + ((EPI == EPI_QKV && n0 >= 1024) ? 1024 : 0)) * K;
  const u16* Abase = A + (size_t)m0 * K;
  // BK64 staging map (round-6 form): wave w rows w*32..+31, 4 insts x 8
  // rows; lane -> row l>>3, src col pre-swizzled (l&7)^((l>>3)&7).
  int grow = w * 32 + (l >> 3);
  int gcol = (((l & 7) ^ ((l >> 3) & 7))) * 8;
  const u16* Ab0 = Abase + (size_t)grow * K + gcol;
  const u16* Bb0 = Bbase + (size_t)grow * K + gcol;
  // MODE 3: per-lane A fragment row pointers (direct global->reg)
  const u16* Arow[4];
  if(MODE == 3){
    #pragma unroll
    for(int mb = 0; mb < 4; mb++)
      Arow[mb] = Abase + (size_t)(m_off + mb*16 + lq) * K + lk*8;
  }

  #define STAGE64(buf, k0)                                                  \
    do{ if(MODE != 3){ _Pragma("unroll")                                    \
      for(int i = 0; i < 4; i++)                                            \
        glds16(Ab0 + (size_t)(i*8) * K + (k0),                              \
               &As[(buf)*TILEU + (w*32 + i*8) * 64]); }                     \
      _Pragma("unroll")                                                     \
      for(int i = 0; i < 4; i++)                                            \
        glds16(Bb0 + (size_t)(i*8) * K + (k0),                              \
               &Bs[(buf)*TILEU + (w*32 + i*8) * 64]);                       \
    } while(0)

  // BK128 staging: 8 insts x 4 rows per operand per wave; row = w*32 +
  // i*4 + (l>>4); src col = ((l&15) ^ (row&15)) * 8. LDS dest linear.
  #define STAGE128(buf, k0)                                                 \
    do{ _Pragma("unroll")                                                   \
      for(int i = 0; i < 8; i++){                                           \
        int rr = i*4 + (l >> 4);                                            \
        int cc = ((l & 15) ^ ((rr + w*32) & 15)) * 8;                       \
        glds16(Abase + (size_t)(w*32 + rr) * K + (k0) + cc,                 \
               &As[(buf)*TILEU + (w*32 + i*4) * 128]);                      \
        glds16(Bbase + (size_t)(w*32 + rr) * K + (k0) + cc,                 \
               &Bs[(buf)*TILEU + (w*32 + i*4) * 128]);                      \
      }                                                                     \
    } while(0)

  #define STAGE(buf, k0)                                                    \
    do{ if(MODE == 2) STAGE128(buf, k0); else STAGE64(buf, k0); } while(0)

  f32x4 acc[4][4] = {};
  #define COMPUTE(buf, kbase)                                                  \
    do{ _Pragma("unroll")                                                      \
      for(int kk = 0; kk < (MODE == 2 ? 4 : 2); kk++){                         \
        bf16x8 af[4], bfr[4];                                                  \
        _Pragma("unroll")                                                      \
        for(int mb = 0; mb < 4; mb++){                                         \
          if(MODE == 3)                                                        \
            af[mb] = *(const bf16x8*)(Arow[mb] + (kbase) + kk*32);             \
          else                                                                 \
            af[mb] = *(const bf16x8*)&As[(buf)*TILEU +                         \
                (m_off + mb*16 + lq) * BK + (((kk*4 + lk) ^ (lq & (BK/8 - 1))) * 8)]; \
        }                                                                      \
        _Pragma("unroll")                                                      \
        for(int nb = 0; nb < 4; nb++)                                          \
          bfr[nb] = *(const bf16x8*)&Bs[(buf)*TILEU +                          \
              (n_off + nb*16 + lq) * BK + (((kk*4 + lk) ^ (lq & (BK/8 - 1))) * 8)]; \
        _Pragma("unroll")                                                      \
        for(int mb = 0; mb < 4; mb++)                                          \
          _Pragma("unroll")                                                    \
          for(int nb = 0; nb < 4; nb++)                                        \
            acc[mb][nb] = mfma16(af[mb], bfr[nb], acc[mb][nb]);                \
      }                                                                        \
    } while(0)

  if(MODE == 1 || MODE == 2){
    int cur = 0;
    STAGE(0, 0);
    __syncthreads();                 // vmcnt(0) drain: tile 0 resident
    for(int k0 = 0; k0 < K; k0 += BK){
      if(k0 + BK < K) STAGE(cur ^ 1, k0 + BK);   // prefetch BEFORE compute
      COMPUTE(cur, k0);
      __syncthreads();               // drains this iter's glds; publishes
      cur ^= 1;
    }
  } else {
    for(int k0 = 0; k0 < K; k0 += 64){
      __syncthreads();               // all waves done reading previous tile
      STAGE64(0, k0);
      __syncthreads();               // vmcnt(0) drain: tile resident
      COMPUTE(0, k0);
    }
  }
  #undef STAGE64
  #undef STAGE128
  #undef STAGE
  #undef COMPUTE

  // epilogue: C/D layout row=(l>>4)*4+r, col=l&15
  #pragma unroll
  for(int mb = 0; mb < 4; mb++)
  #pragma unroll
  for(int nb = 0; nb < 4; nb++){
    #pragma unroll
    for(int r = 0; r < 4; r++){
      int m = m0 + m_off + mb*16 + lk*4 + r;
      int n = n0 + n_off + nb*16 + lq;
      float v = acc[mb][nb][r];
      if(EPI == EPI_QKV){
        int bsrc = (n < 1024) ? n : n + 1024;
        v += loadf(bias, bsrc, bf);
        int bb = m / Tdim, t = m % Tdim;
        if(n < 1024){  // Q -> (B,H,T,D)
          int h = n >> 6, d = n & 63;
          ((u16*)out0)[(((size_t)(bb*Hdim + h)*Tdim + t) << 6) + d] = f2b(v);
        } else {       // V -> transposed (B,H,D,T) for PV B-fragments
          int nv = n - 1024; int h = nv >> 6, d = nv & 63;
          ((u16*)out1)[((size_t)(bb*Hdim + h)*Ddim + d)*Tdim + t] = f2b(v);
        }
      } else if(EPI == EPI_RES){        // x2(f32) = x(INPUT) + A@W + bias
        v += loadf(bias, n, bf) + loadf(res, (size_t)m*N + n, bf);
        ((float*)out0)[(size_t)m*N + n] = v;
      } else if(EPI == EPI_GELU){       // exact gelu -> bf16
        v += loadf(bias, n, bf);
        float gl = 0.5f * v * (1.0f + erff(v * 0.70710678118f));
        ((u16*)out0)[(size_t)m*N + n] = f2b(gl);
      } else {                          // FINAL: x2(f32) + A@W + bias -> OUT
        v += loadf(bias, n, bf) + ((const float*)res)[(size_t)m*N + n];
        size_t oi = (size_t)(mofs + m) * N + n;
        if(bf) ((u16*)out0)[oi] = f2b(v);
        else   ((float*)out0)[oi] = v;
      }
    }
  }
}

// ---------------- fused LIF attention (round-13: shared-tile LDS staging) -
// (unchanged: left the top-5 after round 13; tau hidden by block-coop
// double-buffered staging of the E/V tiles shared by rt=4k..4k+3.)
__global__ __launch_bounds__(256, 3) void attn_k(
    const u16* __restrict__ Q, const u16* __restrict__ Vt, const u16* __restrict__ E,
    const void* __restrict__ gain, const void* __restrict__ battn,
    u16* __restrict__ aout, const int* __restrict__ flagp)
{
  __shared__ u16 Es[2][64][72];    // 18 KB, padded rows (2-way bank max)
  __shared__ u16 Vs[2][64][72];    // 18 KB
  __shared__ u16 P[4][16][72];     // 9 KB, per-wave P band
  int bf = *flagp;
  int k  = 31 - (int)(blockIdx.x >> 5);   // LPT: heavy blocks first
  int bh = blockIdx.x & 31;
  int b = bh >> 4, h = bh & 15;
  int tid = threadIdx.x;
  int w = tid >> 6, l = tid & 63;
  int lq = l & 15, lk = l >> 4;
  int rt = k * 4 + w;              // all 4 rts share stmax = k exactly
  int qrow = rt * 16;
  const u16* Qb = Q  + (size_t)bh * Tdim * Ddim;
  const u16* Vb = Vt + (size_t)bh * Ddim * Tdim;
  const u16* Eh = E  + (size_t)h  * Tdim * Ddim;
  // staging map: 256 thr x 2 segs of 16B cover one 64x64 bf16 tile
  int srow = tid >> 3;             // 0..31 (and +32 for seg 1)
  int scol = (tid & 7) * 8;        // u16 col 0..56
  bf16x8 qf[2];
  #pragma unroll
  for(int ks = 0; ks < 2; ks++)
    qf[ks] = *(const bf16x8*)(Qb + (size_t)(qrow + lq) * Ddim + ks*32 + lk*8);
  float g4[4], b4[4];
  #pragma unroll
  for(int r = 0; r < 4; r++){
    int t = qrow + lk*4 + r;
    g4[r] = loadf(gain, h * Tdim + t, bf);
    b4[r] = loadf(battn, h * Tdim + t, bf);
  }
  bf16x8 onesf;
  #pragma unroll
  for(int j = 0; j < 8; j++) onesf[j] = (short)0x3F80;  // bf16 1.0
  f32x4 num[4] = {};
  f32x4 den4 = {0.f, 0.f, 0.f, 0.f};
  // prologue: stage tile 0 into buffer 0
  {
    bf16x8 e0 = *(const bf16x8*)(Eh + (size_t)(srow     ) * Ddim + scol);
    bf16x8 e1 = *(const bf16x8*)(Eh + (size_t)(srow + 32) * Ddim + scol);
    bf16x8 v0 = *(const bf16x8*)(Vb + (size_t)(srow     ) * Tdim + scol);
    bf16x8 v1 = *(const bf16x8*)(Vb + (size_t)(srow + 32) * Tdim + scol);
    *(bf16x8*)&Es[0][srow     ][scol] = e0;
    *(bf16x8*)&Es[0][srow + 32][scol] = e1;
    *(bf16x8*)&Vs[0][srow     ][scol] = v0;
    *(bf16x8*)&Vs[0][srow + 32][scol] = v1;
  }
  __syncthreads();
  for(int st = 0; st <= k; st++){
    int cur = st & 1;
    // issue next-tile global loads EARLY (latency hides under compute)
    bf16x8 pe0, pe1, pv0, pv1;
    if(st < k){
      pe0 = *(const bf16x8*)(Eh + (size_t)((st+1)*64 + srow     ) * Ddim + scol);
      pe1 = *(const bf16x8*)(Eh + (size_t)((st+1)*64 + srow + 32) * Ddim + scol);
      pv0 = *(const bf16x8*)(Vb + (size_t)(srow     ) * Tdim + (st+1)*64 + scol);
      pv1 = *(const bf16x8*)(Vb + (size_t)(srow + 32) * Tdim + (st+1)*64 + scol);
    }
    // QK^T from LDS
    f32x4 sc[4] = {};
    #pragma unroll
    for(int ks = 0; ks < 2; ks++){
      #pragma unroll
      for(int nb = 0; nb < 4; nb++){
        bf16x8 ef = *(const bf16x8*)&Es[cur][nb*16 + lq][ks*32 + lk*8];
        sc[nb] = mfma16(qf[ks], ef, sc[nb]);
      }
    }
    int diag = (st == k);          // wave-uniform: interior tiles skip mask
    #pragma unroll
    for(int nb = 0; nb < 4; nb++){
      #pragma unroll
      for(int r = 0; r < 4; r++){
        int sg = st*64 + nb*16 + lq;
        int qg = qrow + lk*4 + r;
        float I = fmaf(g4[r], sc[nb][r], b4[r]);
        float u = (I - 1.0f) * __builtin_amdgcn_rcpf(I);
        float L = __builtin_amdgcn_logf(u);
        float denom = fmaf(-0.013862944f, L, 0.002f);
        float e = __builtin_amdgcn_exp2f(0.18033688f * __builtin_amdgcn_rcpf(denom));
        float p = (I > 1.0000001f) ? e : 1.0f;
        if(diag) p = (sg <= qg) ? p : 0.f;
        P[w][lk*4 + r][nb*16 + lq] = f2b(p);
      }
    }
    // wave-private band: in-wave LDS RAW ordered by compiler lgkmcnt waits
    #pragma unroll
    for(int ks = 0; ks < 2; ks++){
      bf16x8 pf = *(const bf16x8*)&P[w][lq][ks*32 + lk*8];
      den4 = mfma16(pf, onesf, den4);   // rowsum -> denominator
      #pragma unroll
      for(int nb = 0; nb < 4; nb++){
        bf16x8 vf = *(const bf16x8*)&Vs[cur][nb*16 + lq][ks*32 + lk*8];
        num[nb] = mfma16(pf, vf, num[nb]);
      }
    }
    if(st < k){
      // write next tile into the other buffer (vmcnt wait auto-inserted),
      // then one barrier: everyone finished reading buf cur^1 last iter.
      *(bf16x8*)&Es[cur^1][srow     ][scol] = pe0;
      *(bf16x8*)&Es[cur^1][srow + 32][scol] = pe1;
      *(bf16x8*)&Vs[cur^1][srow     ][scol] = pv0;
      *(bf16x8*)&Vs[cur^1][srow + 32][scol] = pv1;
      __syncthreads();
    }
  }
  float rden[4];
  #pragma unroll
  for(int r = 0; r < 4; r++) rden[r] = __builtin_amdgcn_rcpf(den4[r]);
  #pragma unroll
  for(int nb = 0; nb < 4; nb++){
    #pragma unroll
    for(int r = 0; r < 4; r++){
      int t = qrow + lk*4 + r;
      int d = nb*16 + lq;
      float o = num[nb][r] * rden[r];
      aout[((size_t)b * Tdim + t) * Cdim + h * Ddim + d] = f2b(o);
    }
  }
}

// --------------------------------------------------------------------------
// Arena (round-8 layout, the measured-best config):
//   flag@0 | R0(8M): xn -> attn_out -> W1t | R1(8M): Wqkv_t -> Wout_t -> W2t
//   | x2(16M f32) | R3a(8M): Q -> hn | R3b(8M): V^T -> gelu quarter | Ebf(4M)
//   | gbuf(32M) @52M iff ws_size >= 85MB -> FULL-M MLP (ran in round 8:
//   GELU 1024 blocks, FINAL 256 blocks — the 563 us path).
extern "C" void kernel_launch(void* const* d_in, const int* in_sizes, int n_in,
                              void* d_out, int out_size, void* d_ws, size_t ws_size,
                              hipStream_t stream)
{
  const void* x      = d_in[0];
  const void* ln1_g  = d_in[1];
  const void* ln1_b  = d_in[2];
  const void* qkv_w  = d_in[3];
  const void* qkv_b  = d_in[4];
  const void* out_w  = d_in[5];
  const void* out_b  = d_in[6];
  const void* ln2_g  = d_in[7];
  const void* ln2_b  = d_in[8];
  const void* mlp_w1 = d_in[9];
  const void* mlp_b1 = d_in[10];
  const void* mlp_w2 = d_in[11];
  const void* mlp_b2 = d_in[12];
  const void* enc    = d_in[13];
  const void* gain   = d_in[14];
  const void* battn  = d_in[15];
  (void)in_sizes; (void)n_in; (void)out_size;

  const size_t MB = 1024 * 1024;
  char* ws = (char*)d_ws;
  int*   flag = (int*)(ws);
  u16*   R0   = (u16*)(ws + 256);
  u16*   R1   = (u16*)(ws + 256 + 8*MB);
  float* x2   = (float*)(ws + 256 + 16*MB);
  u16*   R3a  = (u16*)(ws + 256 + 32*MB);
  u16*   R3b  = (u16*)(ws + 256 + 40*MB);
  u16*   Ebf  = (u16*)(ws + 256 + 48*MB);
  u16*   gbuf = (u16*)(ws + 256 + 52*MB);
  bool fullM = ws_size >= 85*MB;

  dim3 blk(256);
  detect_k<<<1, 64, 0, stream>>>((const u16*)x, flag);
  ln_k<0><<<4096, blk, 0, stream>>>(x, ln1_g, ln1_b, R0, flag);
  transpose_k<<<dim3(3072/32, 1024/32), blk, 0, stream>>>(qkv_w, R1, 1024, 3072, flag);
  cvt_k<<<(Hdim*Tdim*Ddim)/256, blk, 0, stream>>>(enc, Ebf, Hdim*Tdim*Ddim, flag);
  gemm_k<EPI_QKV,1024,0><<<dim3(2048/128, 4096/128), blk, 0, stream>>>(
      R0, R1, qkv_b, R3a, R3b, nullptr, 4096, 2048, 0, flag);
  attn_k<<<dim3(32*32), dim3(256), 0, stream>>>(R3a, R3b, Ebf, gain, battn, R0, flag);
  transpose_k<<<dim3(1024/32, 1024/32), blk, 0, stream>>>(out_w, R1, 1024, 1024, flag);
  gemm_k<EPI_RES,1024,2><<<dim3(1024/128, 4096/128), blk, 0, stream>>>(
      R0, R1, out_b, x2, nullptr, x, 4096, 1024, 0, flag);
  ln_k<1><<<4096, blk, 0, stream>>>(x2, ln2_g, ln2_b, R3a, flag);
  transpose_k<<<dim3(4096/32, 1024/32), blk, 0, stream>>>(mlp_w1, R0, 1024, 4096, flag);
  transpose_k<<<dim3(1024/32, 4096/32), blk, 0, stream>>>(mlp_w2, R1, 4096, 1024, flag);
  if(fullM){
    gemm_k<EPI_GELU,1024,3><<<dim3(4096/128, 4096/128), blk, 0, stream>>>(
        R3a, R0, mlp_b1, gbuf, nullptr, nullptr, 4096, 4096, 0, flag);
    gemm_k<EPI_FINAL,4096,2><<<dim3(1024/128, 4096/128), blk, 0, stream>>>(
        gbuf, R1, mlp_b2, d_out, nullptr, x2, 4096, 1024, 0, flag);
  } else {
    for(int q = 0; q < 4; q++){
      int ro = q * 1024;
      gemm_k<EPI_GELU,1024,2><<<dim3(4096/128, 1024/128), blk, 0, stream>>>(
          R3a + (size_t)ro*1024, R0, mlp_b1, R3b, nullptr, nullptr, 1024, 4096, 0, flag);
      gemm_k<EPI_FINAL,4096,2><<<dim3(1024/128, 1024/128), blk, 0, stream>>>(
          R3b, R1, mlp_b2, d_out, nullptr, x2 + (size_t)ro*1024, 1024, 1024, ro, flag);
    }
  }
}

// Round 11
// 445.808 us; speedup vs baseline: 1.2549x; 1.0871x over previous
//
#include <hip/hip_runtime.h>
#include <math.h>

// Problem: B=2, T=2048, C=1024, H=16, D=64.
// Input/output dtype is sniffed at runtime (f32 vs bf16) — see detect_k.
#define Bdim 2
#define Tdim 2048
#define Cdim 1024
#define Hdim 16
#define Ddim 64

typedef unsigned short u16;
typedef __attribute__((ext_vector_type(8))) short bf16x8;  // 8 bf16 = 4 VGPRs
typedef __attribute__((ext_vector_type(4))) float f32x4;

__device__ __forceinline__ float b2f(u16 s){
  union { float f; unsigned u; } v; v.u = ((unsigned)s) << 16; return v.f;
}
__device__ __forceinline__ u16 f2b(float f){
  union { float f; unsigned u; } v; v.f = f;
  unsigned r = v.u + 0x7fffu + ((v.u >> 16) & 1u);  // RNE
  return (u16)(r >> 16);
}
// flag-dispatched scalar load of an INPUT tensor element (bf=1: bf16, bf=0: f32)
__device__ __forceinline__ float loadf(const void* p, size_t i, int bf){
  float r;
  if(bf) r = b2f(((const u16*)p)[i]);
  else   r = ((const float*)p)[i];
  return r;
}
__device__ __forceinline__ f32x4 mfma16(bf16x8 a, bf16x8 b, f32x4 c){
  return __builtin_amdgcn_mfma_f32_16x16x32_bf16(a, b, c, 0, 0, 0);
}
// async global->LDS, 16B per lane: lds dest = (wave-uniform base) + lane*16,
// global src is per-lane. Dest must be LINEAR (no padding) — rule #21.
__device__ __forceinline__ void glds16(const u16* g, u16* l){
  __builtin_amdgcn_global_load_lds(
      (const __attribute__((address_space(1))) unsigned int*)g,
      (__attribute__((address_space(3))) unsigned int*)l, 16, 0, 0);
}

// ---------------- dtype sniffer -------------------------------------------
__global__ void detect_k(const u16* __restrict__ x, int* __restrict__ flag){
  if(threadIdx.x == 0 && blockIdx.x == 0){
    int sane = 0;
    for(int i = 0; i < 64; i++){
      int e = (x[i] >> 7) & 0xFF;
      sane += (e == 0 || (e >= 0x6E && e <= 0x8A)) ? 1 : 0;
    }
    *flag = (sane >= 56) ? 1 : 0;
  }
}

// ---------------- input convert (enc_hat -> bf16) -------------------------
__global__ __launch_bounds__(256) void cvt_k(const void* __restrict__ in,
    u16* __restrict__ out, int n, const int* __restrict__ flagp){
  int bf = *flagp;
  int i = blockIdx.x * 256 + threadIdx.x;
  if(i < n) out[i] = bf ? ((const u16*)in)[i] : f2b(((const float*)in)[i]);
}

// ---------------- weight transpose: in[K][N] -> out[N][K] (bf16) ----------
__global__ __launch_bounds__(256) void transpose_k(const void* __restrict__ in,
    u16* __restrict__ out, int K, int N, const int* __restrict__ flagp){
  __shared__ u16 tile[32][34];
  int bf = *flagp;
  int n0 = blockIdx.x * 32, k0 = blockIdx.y * 32;
  int tx = threadIdx.x & 31, ty = threadIdx.x >> 5;  // 32 x 8
  #pragma unroll
  for(int i = 0; i < 4; i++)
    tile[ty + i*8][tx] = f2b(loadf(in, (size_t)(k0 + ty + i*8) * N + n0 + tx, bf));
  __syncthreads();
  #pragma unroll
  for(int i = 0; i < 4; i++)
    out[(size_t)(n0 + ty + i*8) * K + k0 + tx] = tile[tx][ty + i*8];
}

// ---------------- LayerNorm over C=1024, one block per row ----------------
template<int SRC>
__global__ __launch_bounds__(256) void ln_k(const void* __restrict__ xin,
    const void* __restrict__ g, const void* __restrict__ be,
    u16* __restrict__ out, const int* __restrict__ flagp){
  __shared__ float red[256];
  int bf = *flagp;
  int row = blockIdx.x, t = threadIdx.x;
  float v[4]; float s = 0.f;
  #pragma unroll
  for(int i = 0; i < 4; i++){
    size_t idx = (size_t)row * Cdim + t + i*256;
    v[i] = (SRC == 1) ? ((const float*)xin)[idx] : loadf(xin, idx, bf);
    s += v[i];
  }
  red[t] = s; __syncthreads();
  for(int o = 128; o > 0; o >>= 1){ if(t < o) red[t] += red[t+o]; __syncthreads(); }
  float mu = red[0] * (1.f / Cdim);
  __syncthreads();
  s = 0.f;
  #pragma unroll
  for(int i = 0; i < 4; i++){ float d = v[i] - mu; s += d*d; }
  red[t] = s; __syncthreads();
  for(int o = 128; o > 0; o >>= 1){ if(t < o) red[t] += red[t+o]; __syncthreads(); }
  float rstd = rsqrtf(red[0] * (1.f / Cdim) + 1e-5f);
  u16* orow = out + (size_t)row * Cdim;
  #pragma unroll
  for(int i = 0; i < 4; i++){
    int c = t + i*256;
    orow[c] = f2b((v[i] - mu) * rstd * loadf(g, c, bf) + loadf(be, c, bf));
  }
}

// ---------------- MFMA GEMM (round-21: exact round-8 modes restored) ------
// Round-20 post-mortem: MODE 3 (A-direct global->reg) regressed GELU
// 77.7 -> 116.7: per-slice global loads sit INSIDE the MFMA dep chain,
// un-hoistable past the barrier. LDS-port model dead (port = ~13% of the
// 2900 cy/block-step). Settled picture across r4-r20: 4-blocks/CU TLP +
// compiler-scheduled single-buffer wins for grid-rich GEMMs (QKV, GELU);
// dbuf BK=128 wins for 1-block/CU GEMMs (RES, FINAL). This is round-8's
// measured-best 451.2 us config, restored verbatim.
// MODE 0: single-buf BK64 | MODE 2: dbuf BK128.
enum { EPI_QKV = 0, EPI_RES = 1, EPI_GELU = 2, EPI_FINAL = 3 };

template<int EPI, int KK, int MODE>
__global__ __launch_bounds__(256) void gemm_k(
    const u16* __restrict__ A, const u16* __restrict__ Bt, const void* __restrict__ bias,
    void* __restrict__ out0, void* __restrict__ out1, const void* __restrict__ res,
    int M, int N, int mofs, const int* __restrict__ flagp)
{
  const int K = KK;
  const int BK    = (MODE == 2) ? 128 : 64;
  const int TILEU = 128 * BK;                  // u16 per operand per buffer
  __shared__ u16 As[(MODE == 2 ? 2 : 1) * 128 * ((MODE == 2) ? 128 : 64)];
  __shared__ u16 Bs[(MODE == 2 ? 2 : 1) * 128 * ((MODE == 2) ? 128 : 64)];
  int bf = *flagp;
  int tid = threadIdx.x;
  // chunked XCD swizzle: contiguous wgid range per XCD (xcd = orig % 8)
  int nblk = (int)(gridDim.x * gridDim.y);
  int orig = (int)(blockIdx.y * gridDim.x + blockIdx.x);
  int wgid = (orig & 7) * (nblk >> 3) + (orig >> 3);
  int bx = wgid % (int)gridDim.x, by = wgid / (int)gridDim.x;
  int m0 = by * 128, n0 = bx * 128;
  int w = tid >> 6, l = tid & 63;
  int lq = l & 15, lk = l >> 4;
  int m_off = (w & 1) * 64, n_off = (w >> 1) * 64;
  // B base: EPI_QKV skip of unused K columns is BLOCK-uniform (1024%128==0)
  const u16* Bbase = Bt +
      (size_t)(n0 + ((EPI == EPI_QKV && n0 >= 1024) ? 1024 : 0)) * K;
  const u16* Abase = A + (size_t)m0 * K;
  // BK64 staging map (round-6 form): wave w rows w*32..+31, 4 insts x 8
  // rows; lane -> row l>>3, src col pre-swizzled (l&7)^((l>>3)&7).
  int grow = w * 32 + (l >> 3);
  int gcol = (((l & 7) ^ ((l >> 3) & 7))) * 8;
  const u16* Ab0 = Abase + (size_t)grow * K + gcol;
  const u16* Bb0 = Bbase + (size_t)grow * K + gcol;

  #define STAGE64(buf, k0)                                                  \
    do{ _Pragma("unroll")                                                   \
      for(int i = 0; i < 4; i++)                                            \
        glds16(Ab0 + (size_t)(i*8) * K + (k0),                              \
               &As[(buf)*TILEU + (w*32 + i*8) * 64]);                       \
      _Pragma("unroll")                                                     \
      for(int i = 0; i < 4; i++)                                            \
        glds16(Bb0 + (size_t)(i*8) * K + (k0),                              \
               &Bs[(buf)*TILEU + (w*32 + i*8) * 64]);                       \
    } while(0)

  // BK128 staging: 8 insts x 4 rows per operand per wave; row = w*32 +
  // i*4 + (l>>4); src col = ((l&15) ^ (row&15)) * 8. LDS dest linear.
  #define STAGE128(buf, k0)                                                 \
    do{ _Pragma("unroll")                                                   \
      for(int i = 0; i < 8; i++){                                           \
        int rr = i*4 + (l >> 4);                                            \
        int cc = ((l & 15) ^ ((rr + w*32) & 15)) * 8;                       \
        glds16(Abase + (size_t)(w*32 + rr) * K + (k0) + cc,                 \
               &As[(buf)*TILEU + (w*32 + i*4) * 128]);                      \
        glds16(Bbase + (size_t)(w*32 + rr) * K + (k0) + cc,                 \
               &Bs[(buf)*TILEU + (w*32 + i*4) * 128]);                      \
      }                                                                     \
    } while(0)

  #define STAGE(buf, k0)                                                    \
    do{ if(MODE == 2) STAGE128(buf, k0); else STAGE64(buf, k0); } while(0)

  f32x4 acc[4][4] = {};
  #define COMPUTE(buf)                                                         \
    do{ _Pragma("unroll")                                                      \
      for(int kk = 0; kk < (MODE == 2 ? 4 : 2); kk++){                         \
        bf16x8 af[4], bfr[4];                                                  \
        _Pragma("unroll")                                                      \
        for(int mb = 0; mb < 4; mb++)                                          \
          af[mb]  = *(const bf16x8*)&As[(buf)*TILEU +                          \
              (m_off + mb*16 + lq) * BK + (((kk*4 + lk) ^ (lq & (BK/8 - 1))) * 8)]; \
        _Pragma("unroll")                                                      \
        for(int nb = 0; nb < 4; nb++)                                          \
          bfr[nb] = *(const bf16x8*)&Bs[(buf)*TILEU +                          \
              (n_off + nb*16 + lq) * BK + (((kk*4 + lk) ^ (lq & (BK/8 - 1))) * 8)]; \
        _Pragma("unroll")                                                      \
        for(int mb = 0; mb < 4; mb++)                                          \
          _Pragma("unroll")                                                    \
          for(int nb = 0; nb < 4; nb++)                                        \
            acc[mb][nb] = mfma16(af[mb], bfr[nb], acc[mb][nb]);                \
      }                                                                        \
    } while(0)

  if(MODE == 2){
    int cur = 0;
    STAGE(0, 0);
    __syncthreads();                 // vmcnt(0) drain: tile 0 resident
    for(int k0 = 0; k0 < K; k0 += BK){
      if(k0 + BK < K) STAGE(cur ^ 1, k0 + BK);   // prefetch BEFORE compute
      COMPUTE(cur);
      __syncthreads();               // drains this iter's glds; publishes
      cur ^= 1;
    }
  } else {
    for(int k0 = 0; k0 < K; k0 += 64){
      __syncthreads();               // all waves done reading previous tile
      STAGE64(0, k0);
      __syncthreads();               // vmcnt(0) drain: tile resident
      COMPUTE(0);
    }
  }
  #undef STAGE64
  #undef STAGE128
  #undef STAGE
  #undef COMPUTE

  // epilogue: C/D layout row=(l>>4)*4+r, col=l&15
  #pragma unroll
  for(int mb = 0; mb < 4; mb++)
  #pragma unroll
  for(int nb = 0; nb < 4; nb++){
    #pragma unroll
    for(int r = 0; r < 4; r++){
      int m = m0 + m_off + mb*16 + lk*4 + r;
      int n = n0 + n_off + nb*16 + lq;
      float v = acc[mb][nb][r];
      if(EPI == EPI_QKV){
        int bsrc = (n < 1024) ? n : n + 1024;
        v += loadf(bias, bsrc, bf);
        int bb = m / Tdim, t = m % Tdim;
        if(n < 1024){  // Q -> (B,H,T,D)
          int h = n >> 6, d = n & 63;
          ((u16*)out0)[(((size_t)(bb*Hdim + h)*Tdim + t) << 6) + d] = f2b(v);
        } else {       // V -> transposed (B,H,D,T) for PV B-fragments
          int nv = n - 1024; int h = nv >> 6, d = nv & 63;
          ((u16*)out1)[((size_t)(bb*Hdim + h)*Ddim + d)*Tdim + t] = f2b(v);
        }
      } else if(EPI == EPI_RES){        // x2(f32) = x(INPUT) + A@W + bias
        v += loadf(bias, n, bf) + loadf(res, (size_t)m*N + n, bf);
        ((float*)out0)[(size_t)m*N + n] = v;
      } else if(EPI == EPI_GELU){       // exact gelu -> bf16
        v += loadf(bias, n, bf);
        float gl = 0.5f * v * (1.0f + erff(v * 0.70710678118f));
        ((u16*)out0)[(size_t)m*N + n] = f2b(gl);
      } else {                          // FINAL: x2(f32) + A@W + bias -> OUT
        v += loadf(bias, n, bf) + ((const float*)res)[(size_t)m*N + n];
        size_t oi = (size_t)(mofs + m) * N + n;
        if(bf) ((u16*)out0)[oi] = f2b(v);
        else   ((float*)out0)[oi] = v;
      }
    }
  }
}

// ---------------- fused LIF attention (round-21: + setprio on MFMA) -------
// Round-13 structure (shared-tile LDS staging, dbuf). New: T5 s_setprio(1)
// around the QK^T and PV MFMA clusters — attn's 4 waves drift across
// phases within a tile (no lockstep barrier between MFMA and LIF-VALU),
// which is the measured regime where setprio pays (+4-7%, m191); GEMM's
// lockstep waves showed ~0 (m190), so this is attn-only.
__global__ __launch_bounds__(256, 3) void attn_k(
    const u16* __restrict__ Q, const u16* __restrict__ Vt, const u16* __restrict__ E,
    const void* __restrict__ gain, const void* __restrict__ battn,
    u16* __restrict__ aout, const int* __restrict__ flagp)
{
  __shared__ u16 Es[2][64][72];    // 18 KB, padded rows (2-way bank max)
  __shared__ u16 Vs[2][64][72];    // 18 KB
  __shared__ u16 P[4][16][72];     // 9 KB, per-wave P band
  int bf = *flagp;
  int k  = 31 - (int)(blockIdx.x >> 5);   // LPT: heavy blocks first
  int bh = blockIdx.x & 31;
  int b = bh >> 4, h = bh & 15;
  int tid = threadIdx.x;
  int w = tid >> 6, l = tid & 63;
  int lq = l & 15, lk = l >> 4;
  int rt = k * 4 + w;              // all 4 rts share stmax = k exactly
  int qrow = rt * 16;
  const u16* Qb = Q  + (size_t)bh * Tdim * Ddim;
  const u16* Vb = Vt + (size_t)bh * Ddim * Tdim;
  const u16* Eh = E  + (size_t)h  * Tdim * Ddim;
  // staging map: 256 thr x 2 segs of 16B cover one 64x64 bf16 tile
  int srow = tid >> 3;             // 0..31 (and +32 for seg 1)
  int scol = (tid & 7) * 8;        // u16 col 0..56
  bf16x8 qf[2];
  #pragma unroll
  for(int ks = 0; ks < 2; ks++)
    qf[ks] = *(const bf16x8*)(Qb + (size_t)(qrow + lq) * Ddim + ks*32 + lk*8);
  float g4[4], b4[4];
  #pragma unroll
  for(int r = 0; r < 4; r++){
    int t = qrow + lk*4 + r;
    g4[r] = loadf(gain, h * Tdim + t, bf);
    b4[r] = loadf(battn, h * Tdim + t, bf);
  }
  bf16x8 onesf;
  #pragma unroll
  for(int j = 0; j < 8; j++) onesf[j] = (short)0x3F80;  // bf16 1.0
  f32x4 num[4] = {};
  f32x4 den4 = {0.f, 0.f, 0.f, 0.f};
  // prologue: stage tile 0 into buffer 0
  {
    bf16x8 e0 = *(const bf16x8*)(Eh + (size_t)(srow     ) * Ddim + scol);
    bf16x8 e1 = *(const bf16x8*)(Eh + (size_t)(srow + 32) * Ddim + scol);
    bf16x8 v0 = *(const bf16x8*)(Vb + (size_t)(srow     ) * Tdim + scol);
    bf16x8 v1 = *(const bf16x8*)(Vb + (size_t)(srow + 32) * Tdim + scol);
    *(bf16x8*)&Es[0][srow     ][scol] = e0;
    *(bf16x8*)&Es[0][srow + 32][scol] = e1;
    *(bf16x8*)&Vs[0][srow     ][scol] = v0;
    *(bf16x8*)&Vs[0][srow + 32][scol] = v1;
  }
  __syncthreads();
  for(int st = 0; st <= k; st++){
    int cur = st & 1;
    // issue next-tile global loads EARLY (latency hides under compute)
    bf16x8 pe0, pe1, pv0, pv1;
    if(st < k){
      pe0 = *(const bf16x8*)(Eh + (size_t)((st+1)*64 + srow     ) * Ddim + scol);
      pe1 = *(const bf16x8*)(Eh + (size_t)((st+1)*64 + srow + 32) * Ddim + scol);
      pv0 = *(const bf16x8*)(Vb + (size_t)(srow     ) * Tdim + (st+1)*64 + scol);
      pv1 = *(const bf16x8*)(Vb + (size_t)(srow + 32) * Tdim + (st+1)*64 + scol);
    }
    // QK^T from LDS
    f32x4 sc[4] = {};
    __builtin_amdgcn_s_setprio(1);
    #pragma unroll
    for(int ks = 0; ks < 2; ks++){
      #pragma unroll
      for(int nb = 0; nb < 4; nb++){
        bf16x8 ef = *(const bf16x8*)&Es[cur][nb*16 + lq][ks*32 + lk*8];
        sc[nb] = mfma16(qf[ks], ef, sc[nb]);
      }
    }
    __builtin_amdgcn_s_setprio(0);
    int diag = (st == k);          // wave-uniform: interior tiles skip mask
    #pragma unroll
    for(int nb = 0; nb < 4; nb++){
      #pragma unroll
      for(int r = 0; r < 4; r++){
        int sg = st*64 + nb*16 + lq;
        int qg = qrow + lk*4 + r;
        float I = fmaf(g4[r], sc[nb][r], b4[r]);
        float u = (I - 1.0f) * __builtin_amdgcn_rcpf(I);
        float L = __builtin_amdgcn_logf(u);
        float denom = fmaf(-0.013862944f, L, 0.002f);
        float e = __builtin_amdgcn_exp2f(0.18033688f * __builtin_amdgcn_rcpf(denom));
        float p = (I > 1.0000001f) ? e : 1.0f;
        if(diag) p = (sg <= qg) ? p : 0.f;
        P[w][lk*4 + r][nb*16 + lq] = f2b(p);
      }
    }
    // wave-private band: in-wave LDS RAW ordered by compiler lgkmcnt waits
    __builtin_amdgcn_s_setprio(1);
    #pragma unroll
    for(int ks = 0; ks < 2; ks++){
      bf16x8 pf = *(const bf16x8*)&P[w][lq][ks*32 + lk*8];
      den4 = mfma16(pf, onesf, den4);   // rowsum -> denominator
      #pragma unroll
      for(int nb = 0; nb < 4; nb++){
        bf16x8 vf = *(const bf16x8*)&Vs[cur][nb*16 + lq][ks*32 + lk*8];
        num[nb] = mfma16(pf, vf, num[nb]);
      }
    }
    __builtin_amdgcn_s_setprio(0);
    if(st < k){
      // write next tile into the other buffer (vmcnt wait auto-inserted),
      // then one barrier: everyone finished reading buf cur^1 last iter.
      *(bf16x8*)&Es[cur^1][srow     ][scol] = pe0;
      *(bf16x8*)&Es[cur^1][srow + 32][scol] = pe1;
      *(bf16x8*)&Vs[cur^1][srow     ][scol] = pv0;
      *(bf16x8*)&Vs[cur^1][srow + 32][scol] = pv1;
      __syncthreads();
    }
  }
  float rden[4];
  #pragma unroll
  for(int r = 0; r < 4; r++) rden[r] = __builtin_amdgcn_rcpf(den4[r]);
  #pragma unroll
  for(int nb = 0; nb < 4; nb++){
    #pragma unroll
    for(int r = 0; r < 4; r++){
      int t = qrow + lk*4 + r;
      int d = nb*16 + lq;
      float o = num[nb][r] * rden[r];
      aout[((size_t)b * Tdim + t) * Cdim + h * Ddim + d] = f2b(o);
    }
  }
}

// --------------------------------------------------------------------------
// Arena (round-8 layout, the measured-best config):
//   flag@0 | R0(8M): xn -> attn_out -> W1t | R1(8M): Wqkv_t -> Wout_t -> W2t
//   | x2(16M f32) | R3a(8M): Q -> hn | R3b(8M): V^T -> gelu quarter | Ebf(4M)
//   | gbuf(32M) @52M iff ws_size >= 85MB -> FULL-M MLP.
extern "C" void kernel_launch(void* const* d_in, const int* in_sizes, int n_in,
                              void* d_out, int out_size, void* d_ws, size_t ws_size,
                              hipStream_t stream)
{
  const void* x      = d_in[0];
  const void* ln1_g  = d_in[1];
  const void* ln1_b  = d_in[2];
  const void* qkv_w  = d_in[3];
  const void* qkv_b  = d_in[4];
  const void* out_w  = d_in[5];
  const void* out_b  = d_in[6];
  const void* ln2_g  = d_in[7];
  const void* ln2_b  = d_in[8];
  const void* mlp_w1 = d_in[9];
  const void* mlp_b1 = d_in[10];
  const void* mlp_w2 = d_in[11];
  const void* mlp_b2 = d_in[12];
  const void* enc    = d_in[13];
  const void* gain   = d_in[14];
  const void* battn  = d_in[15];
  (void)in_sizes; (void)n_in; (void)out_size;

  const size_t MB = 1024 * 1024;
  char* ws = (char*)d_ws;
  int*   flag = (int*)(ws);
  u16*   R0   = (u16*)(ws + 256);
  u16*   R1   = (u16*)(ws + 256 + 8*MB);
  float* x2   = (float*)(ws + 256 + 16*MB);
  u16*   R3a  = (u16*)(ws + 256 + 32*MB);
  u16*   R3b  = (u16*)(ws + 256 + 40*MB);
  u16*   Ebf  = (u16*)(ws + 256 + 48*MB);
  u16*   gbuf = (u16*)(ws + 256 + 52*MB);
  bool fullM = ws_size >= 85*MB;

  dim3 blk(256);
  detect_k<<<1, 64, 0, stream>>>((const u16*)x, flag);
  ln_k<0><<<4096, blk, 0, stream>>>(x, ln1_g, ln1_b, R0, flag);
  transpose_k<<<dim3(3072/32, 1024/32), blk, 0, stream>>>(qkv_w, R1, 1024, 3072, flag);
  cvt_k<<<(Hdim*Tdim*Ddim)/256, blk, 0, stream>>>(enc, Ebf, Hdim*Tdim*Ddim, flag);
  gemm_k<EPI_QKV,1024,0><<<dim3(2048/128, 4096/128), blk, 0, stream>>>(
      R0, R1, qkv_b, R3a, R3b, nullptr, 4096, 2048, 0, flag);
  attn_k<<<dim3(32*32), dim3(256), 0, stream>>>(R3a, R3b, Ebf, gain, battn, R0, flag);
  transpose_k<<<dim3(1024/32, 1024/32), blk, 0, stream>>>(out_w, R1, 1024, 1024, flag);
  gemm_k<EPI_RES,1024,2><<<dim3(1024/128, 4096/128), blk, 0, stream>>>(
      R0, R1, out_b, x2, nullptr, x, 4096, 1024, 0, flag);
  ln_k<1><<<4096, blk, 0, stream>>>(x2, ln2_g, ln2_b, R3a, flag);
  transpose_k<<<dim3(4096/32, 1024/32), blk, 0, stream>>>(mlp_w1, R0, 1024, 4096, flag);
  transpose_k<<<dim3(1024/32, 4096/32), blk, 0, stream>>>(mlp_w2, R1, 4096, 1024, flag);
  if(fullM){
    gemm_k<EPI_GELU,1024,0><<<dim3(4096/128, 4096/128), blk, 0, stream>>>(
        R3a, R0, mlp_b1, gbuf, nullptr, nullptr, 4096, 4096, 0, flag);
    gemm_k<EPI_FINAL,4096,2><<<dim3(1024/128, 4096/128), blk, 0, stream>>>(
        gbuf, R1, mlp_b2, d_out, nullptr, x2, 4096, 1024, 0, flag);
  } else {
    for(int q = 0; q < 4; q++){
      int ro = q * 1024;
      gemm_k<EPI_GELU,1024,2><<<dim3(4096/128, 1024/128), blk, 0, stream>>>(
          R3a + (size_t)ro*1024, R0, mlp_b1, R3b, nullptr, nullptr, 1024, 4096, 0, flag);
      gemm_k<EPI_FINAL,4096,2><<<dim3(1024/128, 1024/128), blk, 0, stream>>>(
          R3b, R1, mlp_b2, d_out, nullptr, x2 + (size_t)ro*1024, 1024, 1024, ro, flag);
    }
  }
}